// Round 1
// baseline (1175.401 us; speedup 1.0000x reference)
//
#include <hip/hip_runtime.h>
#include <cstdint>
#include <cstddef>

#define N_NODES_C 100000
#define N_EDGES_C 1250000
#define N_PAIRS_C 200000
#define IN_DIM_C 128
#define HID_C 64

// ---------------- graph build ----------------

__global__ void k_zero(int* __restrict__ deg, int* __restrict__ cursor, int n) {
    int i = blockIdx.x * blockDim.x + threadIdx.x;
    if (i < n) { deg[i] = 0; cursor[i] = 0; }
}

__global__ void k_count(const int* __restrict__ dst, int* __restrict__ deg, int e) {
    int i = blockIdx.x * blockDim.x + threadIdx.x;
    if (i < e) atomicAdd(&deg[dst[i]], 1);
}

#define SCAN_TPB 256
#define SCAN_IPT 4
#define SCAN_ELEMS 1024

__global__ void k_scan_partial(const int* __restrict__ deg, int* __restrict__ rowptr,
                               int* __restrict__ blocksums, int n) {
    __shared__ int sd[SCAN_TPB];
    int tid = threadIdx.x;
    int base = blockIdx.x * SCAN_ELEMS + tid * SCAN_IPT;
    int v[SCAN_IPT]; int s = 0;
    for (int k = 0; k < SCAN_IPT; k++) { int idx = base + k; v[k] = (idx < n) ? deg[idx] : 0; s += v[k]; }
    sd[tid] = s;
    __syncthreads();
    for (int off = 1; off < SCAN_TPB; off <<= 1) {
        int t = (tid >= off) ? sd[tid - off] : 0;
        __syncthreads();
        sd[tid] += t;
        __syncthreads();
    }
    int excl = sd[tid] - s;   // exclusive prefix of this thread within block
    for (int k = 0; k < SCAN_IPT; k++) { int idx = base + k; if (idx < n) rowptr[idx] = excl; excl += v[k]; }
    if (tid == SCAN_TPB - 1) blocksums[blockIdx.x] = sd[tid];
}

__global__ void k_scan_blocks(int* __restrict__ bs, int nb) {
    __shared__ int sd[128];
    int t = threadIdx.x;
    int v = (t < nb) ? bs[t] : 0;
    sd[t] = v;
    __syncthreads();
    for (int off = 1; off < 128; off <<= 1) {
        int u = (t >= off) ? sd[t - off] : 0;
        __syncthreads();
        sd[t] += u;
        __syncthreads();
    }
    if (t < nb) bs[t] = sd[t] - v;   // exclusive
}

__global__ void k_scan_add(int* __restrict__ rowptr, const int* __restrict__ bs,
                           const int* __restrict__ deg, float* __restrict__ invd,
                           int n, int total) {
    int i = blockIdx.x * blockDim.x + threadIdx.x;
    if (i < n) {
        rowptr[i] += bs[i >> 10];   // SCAN_ELEMS = 1024
        int d = deg[i];
        invd[i] = (d > 0) ? (1.0f / (float)d) : 0.0f;
    }
    if (i == 0) rowptr[n] = total;
}

__global__ void k_fill(const int* __restrict__ src, const int* __restrict__ dst,
                       const int* __restrict__ rowptr, int* __restrict__ cursor,
                       int* __restrict__ adj, int e) {
    int i = blockIdx.x * blockDim.x + threadIdx.x;
    if (i < e) {
        int d = dst[i];
        int pos = rowptr[d] + atomicAdd(&cursor[d], 1);
        adj[pos] = src[i];
    }
}

// ---------------- compute ----------------

// h = relu(x @ W + b); one wave per row, lane = output feature
__global__ __launch_bounds__(256) void k_encoder(const float* __restrict__ x,
        const float* __restrict__ W, const float* __restrict__ b,
        float* __restrict__ h, int n) {
    __shared__ float Ws[IN_DIM_C * HID_C];   // 32 KB
    __shared__ float bs[HID_C];
    for (int i = threadIdx.x; i < IN_DIM_C * HID_C; i += 256) Ws[i] = W[i];
    if (threadIdx.x < HID_C) bs[threadIdx.x] = b[threadIdx.x];
    __syncthreads();
    int wid = threadIdx.x >> 6, lane = threadIdx.x & 63;
    int wave = blockIdx.x * 4 + wid;
    int nw = gridDim.x * 4;
    for (int r = wave; r < n; r += nw) {
        const float* xr = x + (size_t)r * IN_DIM_C;
        float acc = bs[lane];
        #pragma unroll 16
        for (int k = 0; k < IN_DIM_C; k++) acc = fmaf(xr[k], Ws[k * HID_C + lane], acc);
        h[(size_t)r * HID_C + lane] = fmaxf(acc, 0.0f);
    }
}

// agg[node,:] = mean over CSR neighbors of hin[src,:]; one wave per node
__global__ __launch_bounds__(256) void k_aggregate(const int* __restrict__ rowptr,
        const int* __restrict__ adj, const float* __restrict__ invd,
        const float* __restrict__ hin, float* __restrict__ agg, int n) {
    int wid = threadIdx.x >> 6, lane = threadIdx.x & 63;
    int node = blockIdx.x * 4 + wid;
    if (node >= n) return;
    int beg = rowptr[node], end = rowptr[node + 1];
    float acc = 0.0f;
    for (int e = beg; e < end; e++) {
        int s = adj[e];
        acc += hin[(size_t)s * HID_C + lane];
    }
    agg[(size_t)node * HID_C + lane] = acc * invd[node];
}

// hout = relu(agg @ Wl + bl + hin @ Wr)
__global__ __launch_bounds__(256) void k_layer(const float* __restrict__ agg,
        const float* __restrict__ hin, const float* __restrict__ Wl,
        const float* __restrict__ bl, const float* __restrict__ Wr,
        float* __restrict__ hout, int n) {
    __shared__ float Wls[HID_C * HID_C];   // 16 KB
    __shared__ float Wrs[HID_C * HID_C];   // 16 KB
    __shared__ float bs[HID_C];
    for (int i = threadIdx.x; i < HID_C * HID_C; i += 256) { Wls[i] = Wl[i]; Wrs[i] = Wr[i]; }
    if (threadIdx.x < HID_C) bs[threadIdx.x] = bl[threadIdx.x];
    __syncthreads();
    int wid = threadIdx.x >> 6, lane = threadIdx.x & 63;
    int wave = blockIdx.x * 4 + wid;
    int nw = gridDim.x * 4;
    for (int r = wave; r < n; r += nw) {
        const float* ar = agg + (size_t)r * HID_C;
        const float* hr = hin + (size_t)r * HID_C;
        float acc = bs[lane];
        #pragma unroll 8
        for (int k = 0; k < HID_C; k++) {
            acc = fmaf(ar[k], Wls[k * HID_C + lane], acc);
            acc = fmaf(hr[k], Wrs[k * HID_C + lane], acc);
        }
        hout[(size_t)r * HID_C + lane] = fmaxf(acc, 0.0f);
    }
}

// out[p] = relu([h[a],h[b]] @ W1 + b1) @ W2 + b2 ; one wave per pair
__global__ __launch_bounds__(256) void k_pred(const float* __restrict__ h,
        const int* __restrict__ pair, const float* __restrict__ W1,
        const float* __restrict__ b1, const float* __restrict__ W2,
        const float* __restrict__ b2, float* __restrict__ out, int np) {
    __shared__ float W1s[2 * HID_C * HID_C];   // 32 KB
    __shared__ float b1s[HID_C];
    __shared__ float W2s[HID_C];
    for (int i = threadIdx.x; i < 2 * HID_C * HID_C; i += 256) W1s[i] = W1[i];
    if (threadIdx.x < HID_C) { b1s[threadIdx.x] = b1[threadIdx.x]; W2s[threadIdx.x] = W2[threadIdx.x]; }
    __syncthreads();
    int wid = threadIdx.x >> 6, lane = threadIdx.x & 63;
    int wave = blockIdx.x * 4 + wid;
    int nw = gridDim.x * 4;
    float b2v = b2[0];
    for (int p = wave; p < np; p += nw) {
        int a = pair[2 * p], c = pair[2 * p + 1];
        const float* ha = h + (size_t)a * HID_C;
        const float* hb = h + (size_t)c * HID_C;
        float acc = b1s[lane];
        #pragma unroll 8
        for (int k = 0; k < HID_C; k++) {
            acc = fmaf(ha[k], W1s[k * HID_C + lane], acc);
            acc = fmaf(hb[k], W1s[(HID_C + k) * HID_C + lane], acc);
        }
        float v = fmaxf(acc, 0.0f) * W2s[lane];
        #pragma unroll
        for (int off = 32; off > 0; off >>= 1) v += __shfl_down(v, off, 64);
        if (lane == 0) out[p] = v + b2v;
    }
}

// ---------------- launch ----------------

extern "C" void kernel_launch(void* const* d_in, const int* in_sizes, int n_in,
                              void* d_out, int out_size, void* d_ws, size_t ws_size,
                              hipStream_t stream) {
    const float* x    = (const float*)d_in[0];
    const int*   edges= (const int*)d_in[1];     // [2, E] row-major: src then dst
    const int*   pair = (const int*)d_in[2];     // [P, 2]
    const float* encW = (const float*)d_in[3];
    const float* encb = (const float*)d_in[4];
    const float* Wl   = (const float*)d_in[5];   // [3,64,64]
    const float* bl   = (const float*)d_in[6];   // [3,64]
    const float* Wr   = (const float*)d_in[7];   // [3,64,64]
    const float* W1   = (const float*)d_in[8];   // [128,64]
    const float* b1   = (const float*)d_in[9];
    const float* W2   = (const float*)d_in[10];  // [64,1]
    const float* b2   = (const float*)d_in[11];
    float* out = (float*)d_out;

    const int N = N_NODES_C, E = N_EDGES_C, P = N_PAIRS_C;
    const int* src = edges;
    const int* dst = edges + E;

    // workspace layout (~84 MB)
    char* w = (char*)d_ws;
    auto alloc = [&](size_t bytes) { char* p = w; w += (bytes + 255) & ~(size_t)255; return p; };
    int*   deg    = (int*)alloc((size_t)N * 4);
    int*   cursor = (int*)alloc((size_t)N * 4);
    int*   rowptr = (int*)alloc((size_t)(N + 1) * 4);
    int*   bsums  = (int*)alloc(128 * 4);
    float* invd   = (float*)alloc((size_t)N * 4);
    int*   adj    = (int*)alloc((size_t)E * 4);
    float* h0     = (float*)alloc((size_t)N * HID_C * 4);
    float* h1     = (float*)alloc((size_t)N * HID_C * 4);
    float* agg    = (float*)alloc((size_t)N * HID_C * 4);

    int nscan = (N + SCAN_ELEMS - 1) / SCAN_ELEMS;   // 98 (<=128)

    hipLaunchKernelGGL(k_zero, dim3((N + 255) / 256), dim3(256), 0, stream, deg, cursor, N);
    hipLaunchKernelGGL(k_count, dim3((E + 255) / 256), dim3(256), 0, stream, dst, deg, E);
    hipLaunchKernelGGL(k_scan_partial, dim3(nscan), dim3(SCAN_TPB), 0, stream, deg, rowptr, bsums, N);
    hipLaunchKernelGGL(k_scan_blocks, dim3(1), dim3(128), 0, stream, bsums, nscan);
    hipLaunchKernelGGL(k_scan_add, dim3((N + 255) / 256), dim3(256), 0, stream, rowptr, bsums, deg, invd, N, E);
    hipLaunchKernelGGL(k_fill, dim3((E + 255) / 256), dim3(256), 0, stream, src, dst, rowptr, cursor, adj, E);

    hipLaunchKernelGGL(k_encoder, dim3(1024), dim3(256), 0, stream, x, encW, encb, h0, N);

    float* hc = h0; float* hn = h1;
    for (int l = 0; l < 3; l++) {
        hipLaunchKernelGGL(k_aggregate, dim3((N + 3) / 4), dim3(256), 0, stream,
                           rowptr, adj, invd, hc, agg, N);
        hipLaunchKernelGGL(k_layer, dim3(1024), dim3(256), 0, stream,
                           agg, hc, Wl + (size_t)l * HID_C * HID_C, bl + (size_t)l * HID_C,
                           Wr + (size_t)l * HID_C * HID_C, hn, N);
        float* t = hc; hc = hn; hn = t;
    }

    hipLaunchKernelGGL(k_pred, dim3(1024), dim3(256), 0, stream, hc, pair, W1, b1, W2, b2, out, P);
}

// Round 2
// 774.375 us; speedup vs baseline: 1.5179x; 1.5179x over previous
//
#include <hip/hip_runtime.h>
#include <cstdint>
#include <cstddef>

#define N_NODES_C 100000
#define N_EDGES_C 1250000
#define N_PAIRS_C 200000
#define IN_DIM_C 128
#define HID_C 64

// ---------------- graph build ----------------

__global__ void k_zero(int* __restrict__ deg, int* __restrict__ cursor, int n) {
    int i = blockIdx.x * blockDim.x + threadIdx.x;
    if (i < n) { deg[i] = 0; cursor[i] = 0; }
}

__global__ void k_count(const int* __restrict__ dst, int* __restrict__ deg, int e) {
    int i = blockIdx.x * blockDim.x + threadIdx.x;
    if (i < e) atomicAdd(&deg[dst[i]], 1);
}

#define SCAN_TPB 256
#define SCAN_IPT 4
#define SCAN_ELEMS 1024

__global__ void k_scan_partial(const int* __restrict__ deg, int* __restrict__ rowptr,
                               int* __restrict__ blocksums, int n) {
    __shared__ int sd[SCAN_TPB];
    int tid = threadIdx.x;
    int base = blockIdx.x * SCAN_ELEMS + tid * SCAN_IPT;
    int v[SCAN_IPT]; int s = 0;
    for (int k = 0; k < SCAN_IPT; k++) { int idx = base + k; v[k] = (idx < n) ? deg[idx] : 0; s += v[k]; }
    sd[tid] = s;
    __syncthreads();
    for (int off = 1; off < SCAN_TPB; off <<= 1) {
        int t = (tid >= off) ? sd[tid - off] : 0;
        __syncthreads();
        sd[tid] += t;
        __syncthreads();
    }
    int excl = sd[tid] - s;
    for (int k = 0; k < SCAN_IPT; k++) { int idx = base + k; if (idx < n) rowptr[idx] = excl; excl += v[k]; }
    if (tid == SCAN_TPB - 1) blocksums[blockIdx.x] = sd[tid];
}

__global__ void k_scan_blocks(int* __restrict__ bs, int nb) {
    __shared__ int sd[128];
    int t = threadIdx.x;
    int v = (t < nb) ? bs[t] : 0;
    sd[t] = v;
    __syncthreads();
    for (int off = 1; off < 128; off <<= 1) {
        int u = (t >= off) ? sd[t - off] : 0;
        __syncthreads();
        sd[t] += u;
        __syncthreads();
    }
    if (t < nb) bs[t] = sd[t] - v;
}

__global__ void k_scan_add(int* __restrict__ rowptr, const int* __restrict__ bs,
                           const int* __restrict__ deg, float* __restrict__ invd,
                           int n, int total) {
    int i = blockIdx.x * blockDim.x + threadIdx.x;
    if (i < n) {
        rowptr[i] += bs[i >> 10];
        int d = deg[i];
        invd[i] = (d > 0) ? (1.0f / (float)d) : 0.0f;
    }
    if (i == 0) rowptr[n] = total;
}

__global__ void k_fill(const int* __restrict__ src, const int* __restrict__ dst,
                       const int* __restrict__ rowptr, int* __restrict__ cursor,
                       int* __restrict__ adj, int e) {
    int i = blockIdx.x * blockDim.x + threadIdx.x;
    if (i < e) {
        int d = dst[i];
        int pos = rowptr[d] + atomicAdd(&cursor[d], 1);
        adj[pos] = src[i];
    }
}

// ---------------- aggregation (unchanged this round) ----------------

__global__ __launch_bounds__(256) void k_aggregate(const int* __restrict__ rowptr,
        const int* __restrict__ adj, const float* __restrict__ invd,
        const float* __restrict__ hin, float* __restrict__ agg, int n) {
    int wid = threadIdx.x >> 6, lane = threadIdx.x & 63;
    int node = blockIdx.x * 4 + wid;
    if (node >= n) return;
    int beg = rowptr[node], end = rowptr[node + 1];
    float acc = 0.0f;
    for (int e = beg; e < end; e++) {
        int s = adj[e];
        acc += hin[(size_t)s * HID_C + lane];
    }
    agg[(size_t)node * HID_C + lane] = acc * invd[node];
}

// ---------------- tiled GEMM (64 rows x 64 cols, K=128, thread = 4x4 tile) ----
// MODE 0: encoder  A-row = x[g][0:128]                 W = encW[128][64]
// MODE 1: layer    A-row = agg[g][0:64] ++ hin[g][0:64] W = [Wl;Wr]
// MODE 2: pred     A-row = h[a_g] ++ h[b_g]             W = W1, + fused @W2+b2
//
// A staged transposed in LDS with XOR swizzle: addr(k,r) = k*64 + (r ^ 4*((k>>2)&15))
//   -> b128 reads of 4 rows at fixed k are 2-way-bank (free); transpose writes 4-way
//      on negligible volume. W stays k-major (reads broadcast, 2-way).
// Per k-step per wave: 2 ds_read_b128 (~24 cyc) + 16 fma (~32 cyc) -> fma-bound.

__device__ __forceinline__ float4 ld4(const float* p) { return *(const float4*)p; }

template<int MODE>
__global__ __launch_bounds__(256, 2) void k_gemm(
    const float* __restrict__ A1, const float* __restrict__ A2,
    const int* __restrict__ pidx,
    const float* __restrict__ Ws1, const float* __restrict__ Ws2,
    const float* __restrict__ bias, const float* __restrict__ W2p,
    const float* __restrict__ b2p,
    float* __restrict__ outp, int nrows)
{
    __shared__ float AT[128 * 64];   // 32 KB, transposed+swizzled
    __shared__ float Wm[128 * 64];   // 32 KB, k-major
    const int t = threadIdx.x;
    const int g0 = blockIdx.x * 64;

    // stage W: 16 consecutive lanes load one 256B W row, b128 LDS write
    #pragma unroll
    for (int p = 0; p < 8; ++p) {
        int k = p * 16 + (t >> 4);
        int c4 = (t & 15) * 4;
        float4 wv;
        if (MODE == 1) wv = (k < 64) ? ld4(Ws1 + k * 64 + c4) : ld4(Ws2 + (k - 64) * 64 + c4);
        else           wv = ld4(Ws1 + k * 64 + c4);
        *(float4*)&Wm[k * 64 + c4] = wv;
    }
    // stage A: 16/32 consecutive lanes read one source row coalesced; transpose into AT
    #pragma unroll
    for (int p = 0; p < 8; ++p) {
        int r = p * 8 + (t >> 5);
        int c = t & 31;                 // float4-chunk 0..31 of the 128-float A row
        int g = g0 + r; if (g > nrows - 1) g = nrows - 1;
        const float* ptr;
        if (MODE == 0)      ptr = A1 + (size_t)g * 128 + c * 4;
        else if (MODE == 1) ptr = (c < 16) ? (A1 + (size_t)g * 64 + c * 4)
                                           : (A2 + (size_t)g * 64 + (c - 16) * 4);
        else { int idx = pidx[2 * g + (c >> 4)]; ptr = A1 + (size_t)idx * 64 + (c & 15) * 4; }
        float4 av = ld4(ptr);
        int rs = r ^ ((c & 15) * 4);    // swizzle; k>>2 == c for all 4 elements
        int base = c * 256 + rs;        // (4c)*64 + rs
        AT[base      ] = av.x;
        AT[base +  64] = av.y;
        AT[base + 128] = av.z;
        AT[base + 192] = av.w;
    }
    __syncthreads();

    const int tc = t & 15, tr = t >> 4;
    const int tc4 = tc * 4, tr4 = tr * 4;
    float4 acc0 = {0, 0, 0, 0}, acc1 = acc0, acc2 = acc0, acc3 = acc0;

    #pragma unroll 4
    for (int kc = 0; kc < 32; ++kc) {
        int abase = kc * 256 + (tr4 ^ ((kc & 15) * 4));
        int wbase = kc * 256 + tc4;
        #pragma unroll
        for (int i = 0; i < 4; ++i) {
            float4 aw = ld4(&AT[abase + i * 64]);   // rows tr4..tr4+3 at k=4kc+i
            float4 ww = ld4(&Wm[wbase + i * 64]);   // cols tc4..tc4+3 at k
            acc0.x = fmaf(aw.x, ww.x, acc0.x); acc0.y = fmaf(aw.x, ww.y, acc0.y);
            acc0.z = fmaf(aw.x, ww.z, acc0.z); acc0.w = fmaf(aw.x, ww.w, acc0.w);
            acc1.x = fmaf(aw.y, ww.x, acc1.x); acc1.y = fmaf(aw.y, ww.y, acc1.y);
            acc1.z = fmaf(aw.y, ww.z, acc1.z); acc1.w = fmaf(aw.y, ww.w, acc1.w);
            acc2.x = fmaf(aw.z, ww.x, acc2.x); acc2.y = fmaf(aw.z, ww.y, acc2.y);
            acc2.z = fmaf(aw.z, ww.z, acc2.z); acc2.w = fmaf(aw.z, ww.w, acc2.w);
            acc3.x = fmaf(aw.w, ww.x, acc3.x); acc3.y = fmaf(aw.w, ww.y, acc3.y);
            acc3.z = fmaf(aw.w, ww.z, acc3.z); acc3.w = fmaf(aw.w, ww.w, acc3.w);
        }
    }

    float4 bv = ld4(bias + tc4);
    float4 accs[4] = {acc0, acc1, acc2, acc3};
    if (MODE == 2) {
        float4 w2 = ld4(W2p + tc4);
        float bb = b2p[0];
        #pragma unroll
        for (int i = 0; i < 4; ++i) {
            float zx = fmaxf(accs[i].x + bv.x, 0.f);
            float zy = fmaxf(accs[i].y + bv.y, 0.f);
            float zz = fmaxf(accs[i].z + bv.z, 0.f);
            float zw = fmaxf(accs[i].w + bv.w, 0.f);
            float v = zx * w2.x + zy * w2.y + zz * w2.z + zw * w2.w;
            v += __shfl_down(v, 8, 64);
            v += __shfl_down(v, 4, 64);
            v += __shfl_down(v, 2, 64);
            v += __shfl_down(v, 1, 64);
            if (tc == 0) {
                int g = g0 + tr4 + i;
                if (g < nrows) outp[g] = v + bb;
            }
        }
    } else {
        #pragma unroll
        for (int i = 0; i < 4; ++i) {
            int g = g0 + tr4 + i;
            if (g < nrows) {
                float4 o;
                o.x = fmaxf(accs[i].x + bv.x, 0.f);
                o.y = fmaxf(accs[i].y + bv.y, 0.f);
                o.z = fmaxf(accs[i].z + bv.z, 0.f);
                o.w = fmaxf(accs[i].w + bv.w, 0.f);
                *(float4*)&outp[(size_t)g * 64 + tc4] = o;
            }
        }
    }
}

// ---------------- launch ----------------

extern "C" void kernel_launch(void* const* d_in, const int* in_sizes, int n_in,
                              void* d_out, int out_size, void* d_ws, size_t ws_size,
                              hipStream_t stream) {
    const float* x    = (const float*)d_in[0];
    const int*   edges= (const int*)d_in[1];
    const int*   pair = (const int*)d_in[2];
    const float* encW = (const float*)d_in[3];
    const float* encb = (const float*)d_in[4];
    const float* Wl   = (const float*)d_in[5];
    const float* bl   = (const float*)d_in[6];
    const float* Wr   = (const float*)d_in[7];
    const float* W1   = (const float*)d_in[8];
    const float* b1   = (const float*)d_in[9];
    const float* W2   = (const float*)d_in[10];
    const float* b2   = (const float*)d_in[11];
    float* out = (float*)d_out;

    const int N = N_NODES_C, E = N_EDGES_C, P = N_PAIRS_C;
    const int* src = edges;
    const int* dst = edges + E;

    char* w = (char*)d_ws;
    auto alloc = [&](size_t bytes) { char* p = w; w += (bytes + 255) & ~(size_t)255; return p; };
    int*   deg    = (int*)alloc((size_t)N * 4);
    int*   cursor = (int*)alloc((size_t)N * 4);
    int*   rowptr = (int*)alloc((size_t)(N + 1) * 4);
    int*   bsums  = (int*)alloc(128 * 4);
    float* invd   = (float*)alloc((size_t)N * 4);
    int*   adj    = (int*)alloc((size_t)E * 4);
    float* h0     = (float*)alloc((size_t)N * HID_C * 4);
    float* h1     = (float*)alloc((size_t)N * HID_C * 4);
    float* agg    = (float*)alloc((size_t)N * HID_C * 4);

    int nscan = (N + SCAN_ELEMS - 1) / SCAN_ELEMS;

    hipLaunchKernelGGL(k_zero, dim3((N + 255) / 256), dim3(256), 0, stream, deg, cursor, N);
    hipLaunchKernelGGL(k_count, dim3((E + 255) / 256), dim3(256), 0, stream, dst, deg, E);
    hipLaunchKernelGGL(k_scan_partial, dim3(nscan), dim3(SCAN_TPB), 0, stream, deg, rowptr, bsums, N);
    hipLaunchKernelGGL(k_scan_blocks, dim3(1), dim3(128), 0, stream, bsums, nscan);
    hipLaunchKernelGGL(k_scan_add, dim3((N + 255) / 256), dim3(256), 0, stream, rowptr, bsums, deg, invd, N, E);
    hipLaunchKernelGGL(k_fill, dim3((E + 255) / 256), dim3(256), 0, stream, src, dst, rowptr, cursor, adj, E);

    const int NB_N = (N + 63) / 64;   // 1563
    const int NB_P = (P + 63) / 64;   // 3125

    // encoder
    k_gemm<0><<<dim3(NB_N), dim3(256), 0, stream>>>(
        x, nullptr, nullptr, encW, nullptr, encb, nullptr, nullptr, h0, N);

    float* hc = h0; float* hn = h1;
    for (int l = 0; l < 3; l++) {
        hipLaunchKernelGGL(k_aggregate, dim3((N + 3) / 4), dim3(256), 0, stream,
                           rowptr, adj, invd, hc, agg, N);
        k_gemm<1><<<dim3(NB_N), dim3(256), 0, stream>>>(
            agg, hc, nullptr, Wl + (size_t)l * 64 * 64, Wr + (size_t)l * 64 * 64,
            bl + (size_t)l * 64, nullptr, nullptr, hn, N);
        float* tswap = hc; hc = hn; hn = tswap;
    }

    k_gemm<2><<<dim3(NB_P), dim3(256), 0, stream>>>(
        hc, nullptr, pair, W1, nullptr, b1, W2, b2, out, P);
}

// Round 3
// 543.670 us; speedup vs baseline: 2.1620x; 1.4243x over previous
//
#include <hip/hip_runtime.h>
#include <cstdint>
#include <cstddef>

#define N_NODES_C 100000
#define N_EDGES_C 1250000
#define N_PAIRS_C 200000
#define IN_DIM_C 128
#define HID_C 64

// ---------------- graph build ----------------

__global__ void k_zero(int* __restrict__ deg, int* __restrict__ cursor, int n) {
    int i = blockIdx.x * blockDim.x + threadIdx.x;
    if (i < n) { deg[i] = 0; cursor[i] = 0; }
}

__global__ void k_count(const int* __restrict__ dst, int* __restrict__ deg, int e) {
    int i = blockIdx.x * blockDim.x + threadIdx.x;
    if (i < e) atomicAdd(&deg[dst[i]], 1);
}

#define SCAN_TPB 256
#define SCAN_IPT 4
#define SCAN_ELEMS 1024

__global__ void k_scan_partial(const int* __restrict__ deg, int* __restrict__ rowptr,
                               int* __restrict__ blocksums, int n) {
    __shared__ int sd[SCAN_TPB];
    int tid = threadIdx.x;
    int base = blockIdx.x * SCAN_ELEMS + tid * SCAN_IPT;
    int v[SCAN_IPT]; int s = 0;
    for (int k = 0; k < SCAN_IPT; k++) { int idx = base + k; v[k] = (idx < n) ? deg[idx] : 0; s += v[k]; }
    sd[tid] = s;
    __syncthreads();
    for (int off = 1; off < SCAN_TPB; off <<= 1) {
        int t = (tid >= off) ? sd[tid - off] : 0;
        __syncthreads();
        sd[tid] += t;
        __syncthreads();
    }
    int excl = sd[tid] - s;
    for (int k = 0; k < SCAN_IPT; k++) { int idx = base + k; if (idx < n) rowptr[idx] = excl; excl += v[k]; }
    if (tid == SCAN_TPB - 1) blocksums[blockIdx.x] = sd[tid];
}

__global__ void k_scan_blocks(int* __restrict__ bs, int nb) {
    __shared__ int sd[128];
    int t = threadIdx.x;
    int v = (t < nb) ? bs[t] : 0;
    sd[t] = v;
    __syncthreads();
    for (int off = 1; off < 128; off <<= 1) {
        int u = (t >= off) ? sd[t - off] : 0;
        __syncthreads();
        sd[t] += u;
        __syncthreads();
    }
    if (t < nb) bs[t] = sd[t] - v;
}

__global__ void k_scan_add(int* __restrict__ rowptr, const int* __restrict__ bs,
                           const int* __restrict__ deg, float* __restrict__ invd,
                           int n, int total) {
    int i = blockIdx.x * blockDim.x + threadIdx.x;
    if (i < n) {
        rowptr[i] += bs[i >> 10];
        int d = deg[i];
        invd[i] = (d > 0) ? (1.0f / (float)d) : 0.0f;
    }
    if (i == 0) rowptr[n] = total;
}

__global__ void k_fill(const int* __restrict__ src, const int* __restrict__ dst,
                       const int* __restrict__ rowptr, int* __restrict__ cursor,
                       int* __restrict__ adj, int e) {
    int i = blockIdx.x * blockDim.x + threadIdx.x;
    if (i < e) {
        int d = dst[i];
        int pos = rowptr[d] + atomicAdd(&cursor[d], 1);
        adj[pos] = src[i];
    }
}

// ---------------- aggregation ----------------
// One wave per node, lane = feature. 8-wide manual unroll: 8 independent
// wave-uniform adj loads, then 8 independent 256B row gathers, then
// predicated accumulate. Tail chunks clamp the index (duplicate-address
// load, L1-absorbed) and add 0. Breaks the serial adj->row latency chain:
// ~2*ceil(deg/8) latency epochs per node instead of ~2*deg.

__global__ __launch_bounds__(256) void k_aggregate(const int* __restrict__ rowptr,
        const int* __restrict__ adj, const float* __restrict__ invd,
        const float* __restrict__ hin, float* __restrict__ agg, int n) {
    int wid = threadIdx.x >> 6, lane = threadIdx.x & 63;
    int node = blockIdx.x * 4 + wid;
    if (node >= n) return;
    int beg = rowptr[node], end = rowptr[node + 1];
    float acc = 0.0f;
    for (int e = beg; e < end; e += 8) {
        int idx[8];
        #pragma unroll
        for (int j = 0; j < 8; ++j) {
            int ee = e + j;
            idx[j] = adj[ee < end ? ee : end - 1];
        }
        float v[8];
        #pragma unroll
        for (int j = 0; j < 8; ++j) v[j] = hin[(size_t)idx[j] * HID_C + lane];
        #pragma unroll
        for (int j = 0; j < 8; ++j) acc += (e + j < end) ? v[j] : 0.0f;
    }
    agg[(size_t)node * HID_C + lane] = acc * invd[node];
}

// ---------------- tiled GEMM (64 rows x 64 cols, K=128, thread = 4x4 tile) ----
// MODE 0: encoder  A-row = x[g][0:128]                 W = encW[128][64]
// MODE 1: layer    A-row = agg[g][0:64] ++ hin[g][0:64] W = [Wl;Wr]
// MODE 2: pred     A-row = h[a_g] ++ h[b_g]             W = W1, + fused @W2+b2

__device__ __forceinline__ float4 ld4(const float* p) { return *(const float4*)p; }

template<int MODE>
__global__ __launch_bounds__(256, 2) void k_gemm(
    const float* __restrict__ A1, const float* __restrict__ A2,
    const int* __restrict__ pidx,
    const float* __restrict__ Ws1, const float* __restrict__ Ws2,
    const float* __restrict__ bias, const float* __restrict__ W2p,
    const float* __restrict__ b2p,
    float* __restrict__ outp, int nrows)
{
    __shared__ float AT[128 * 64];   // 32 KB, transposed+swizzled
    __shared__ float Wm[128 * 64];   // 32 KB, k-major
    const int t = threadIdx.x;
    const int g0 = blockIdx.x * 64;

    #pragma unroll
    for (int p = 0; p < 8; ++p) {
        int k = p * 16 + (t >> 4);
        int c4 = (t & 15) * 4;
        float4 wv;
        if (MODE == 1) wv = (k < 64) ? ld4(Ws1 + k * 64 + c4) : ld4(Ws2 + (k - 64) * 64 + c4);
        else           wv = ld4(Ws1 + k * 64 + c4);
        *(float4*)&Wm[k * 64 + c4] = wv;
    }
    #pragma unroll
    for (int p = 0; p < 8; ++p) {
        int r = p * 8 + (t >> 5);
        int c = t & 31;
        int g = g0 + r; if (g > nrows - 1) g = nrows - 1;
        const float* ptr;
        if (MODE == 0)      ptr = A1 + (size_t)g * 128 + c * 4;
        else if (MODE == 1) ptr = (c < 16) ? (A1 + (size_t)g * 64 + c * 4)
                                           : (A2 + (size_t)g * 64 + (c - 16) * 4);
        else { int idx = pidx[2 * g + (c >> 4)]; ptr = A1 + (size_t)idx * 64 + (c & 15) * 4; }
        float4 av = ld4(ptr);
        int rs = r ^ ((c & 15) * 4);
        int base = c * 256 + rs;
        AT[base      ] = av.x;
        AT[base +  64] = av.y;
        AT[base + 128] = av.z;
        AT[base + 192] = av.w;
    }
    __syncthreads();

    const int tc = t & 15, tr = t >> 4;
    const int tc4 = tc * 4, tr4 = tr * 4;
    float4 acc0 = {0, 0, 0, 0}, acc1 = acc0, acc2 = acc0, acc3 = acc0;

    #pragma unroll 4
    for (int kc = 0; kc < 32; ++kc) {
        int abase = kc * 256 + (tr4 ^ ((kc & 15) * 4));
        int wbase = kc * 256 + tc4;
        #pragma unroll
        for (int i = 0; i < 4; ++i) {
            float4 aw = ld4(&AT[abase + i * 64]);
            float4 ww = ld4(&Wm[wbase + i * 64]);
            acc0.x = fmaf(aw.x, ww.x, acc0.x); acc0.y = fmaf(aw.x, ww.y, acc0.y);
            acc0.z = fmaf(aw.x, ww.z, acc0.z); acc0.w = fmaf(aw.x, ww.w, acc0.w);
            acc1.x = fmaf(aw.y, ww.x, acc1.x); acc1.y = fmaf(aw.y, ww.y, acc1.y);
            acc1.z = fmaf(aw.y, ww.z, acc1.z); acc1.w = fmaf(aw.y, ww.w, acc1.w);
            acc2.x = fmaf(aw.z, ww.x, acc2.x); acc2.y = fmaf(aw.z, ww.y, acc2.y);
            acc2.z = fmaf(aw.z, ww.z, acc2.z); acc2.w = fmaf(aw.z, ww.w, acc2.w);
            acc3.x = fmaf(aw.w, ww.x, acc3.x); acc3.y = fmaf(aw.w, ww.y, acc3.y);
            acc3.z = fmaf(aw.w, ww.z, acc3.z); acc3.w = fmaf(aw.w, ww.w, acc3.w);
        }
    }

    float4 bv = ld4(bias + tc4);
    float4 accs[4] = {acc0, acc1, acc2, acc3};
    if (MODE == 2) {
        float4 w2 = ld4(W2p + tc4);
        float bb = b2p[0];
        #pragma unroll
        for (int i = 0; i < 4; ++i) {
            float zx = fmaxf(accs[i].x + bv.x, 0.f);
            float zy = fmaxf(accs[i].y + bv.y, 0.f);
            float zz = fmaxf(accs[i].z + bv.z, 0.f);
            float zw = fmaxf(accs[i].w + bv.w, 0.f);
            float v = zx * w2.x + zy * w2.y + zz * w2.z + zw * w2.w;
            v += __shfl_down(v, 8, 64);
            v += __shfl_down(v, 4, 64);
            v += __shfl_down(v, 2, 64);
            v += __shfl_down(v, 1, 64);
            if (tc == 0) {
                int g = g0 + tr4 + i;
                if (g < nrows) outp[g] = v + bb;
            }
        }
    } else {
        #pragma unroll
        for (int i = 0; i < 4; ++i) {
            int g = g0 + tr4 + i;
            if (g < nrows) {
                float4 o;
                o.x = fmaxf(accs[i].x + bv.x, 0.f);
                o.y = fmaxf(accs[i].y + bv.y, 0.f);
                o.z = fmaxf(accs[i].z + bv.z, 0.f);
                o.w = fmaxf(accs[i].w + bv.w, 0.f);
                *(float4*)&outp[(size_t)g * 64 + tc4] = o;
            }
        }
    }
}

// ---------------- launch ----------------

extern "C" void kernel_launch(void* const* d_in, const int* in_sizes, int n_in,
                              void* d_out, int out_size, void* d_ws, size_t ws_size,
                              hipStream_t stream) {
    const float* x    = (const float*)d_in[0];
    const int*   edges= (const int*)d_in[1];
    const int*   pair = (const int*)d_in[2];
    const float* encW = (const float*)d_in[3];
    const float* encb = (const float*)d_in[4];
    const float* Wl   = (const float*)d_in[5];
    const float* bl   = (const float*)d_in[6];
    const float* Wr   = (const float*)d_in[7];
    const float* W1   = (const float*)d_in[8];
    const float* b1   = (const float*)d_in[9];
    const float* W2   = (const float*)d_in[10];
    const float* b2   = (const float*)d_in[11];
    float* out = (float*)d_out;

    const int N = N_NODES_C, E = N_EDGES_C, P = N_PAIRS_C;
    const int* src = edges;
    const int* dst = edges + E;

    char* w = (char*)d_ws;
    auto alloc = [&](size_t bytes) { char* p = w; w += (bytes + 255) & ~(size_t)255; return p; };
    int*   deg    = (int*)alloc((size_t)N * 4);
    int*   cursor = (int*)alloc((size_t)N * 4);
    int*   rowptr = (int*)alloc((size_t)(N + 1) * 4);
    int*   bsums  = (int*)alloc(128 * 4);
    float* invd   = (float*)alloc((size_t)N * 4);
    int*   adj    = (int*)alloc((size_t)E * 4);
    float* h0     = (float*)alloc((size_t)N * HID_C * 4);
    float* h1     = (float*)alloc((size_t)N * HID_C * 4);
    float* agg    = (float*)alloc((size_t)N * HID_C * 4);

    int nscan = (N + SCAN_ELEMS - 1) / SCAN_ELEMS;

    hipLaunchKernelGGL(k_zero, dim3((N + 255) / 256), dim3(256), 0, stream, deg, cursor, N);
    hipLaunchKernelGGL(k_count, dim3((E + 255) / 256), dim3(256), 0, stream, dst, deg, E);
    hipLaunchKernelGGL(k_scan_partial, dim3(nscan), dim3(SCAN_TPB), 0, stream, deg, rowptr, bsums, N);
    hipLaunchKernelGGL(k_scan_blocks, dim3(1), dim3(128), 0, stream, bsums, nscan);
    hipLaunchKernelGGL(k_scan_add, dim3((N + 255) / 256), dim3(256), 0, stream, rowptr, bsums, deg, invd, N, E);
    hipLaunchKernelGGL(k_fill, dim3((E + 255) / 256), dim3(256), 0, stream, src, dst, rowptr, cursor, adj, E);

    const int NB_N = (N + 63) / 64;
    const int NB_P = (P + 63) / 64;

    k_gemm<0><<<dim3(NB_N), dim3(256), 0, stream>>>(
        x, nullptr, nullptr, encW, nullptr, encb, nullptr, nullptr, h0, N);

    float* hc = h0; float* hn = h1;
    for (int l = 0; l < 3; l++) {
        hipLaunchKernelGGL(k_aggregate, dim3((N + 3) / 4), dim3(256), 0, stream,
                           rowptr, adj, invd, hc, agg, N);
        k_gemm<1><<<dim3(NB_N), dim3(256), 0, stream>>>(
            agg, hc, nullptr, Wl + (size_t)l * 64 * 64, Wr + (size_t)l * 64 * 64,
            bl + (size_t)l * 64, nullptr, nullptr, hn, N);
        float* tswap = hc; hc = hn; hn = tswap;
    }

    k_gemm<2><<<dim3(NB_P), dim3(256), 0, stream>>>(
        hc, nullptr, pair, W1, nullptr, b1, W2, b2, out, P);
}

// Round 4
// 467.946 us; speedup vs baseline: 2.5118x; 1.1618x over previous
//
#include <hip/hip_runtime.h>
#include <cstdint>
#include <cstddef>

#define N_NODES_C 100000
#define N_EDGES_C 1250000
#define N_PAIRS_C 200000
#define IN_DIM_C 128
#define HID_C 64

// graph-build geometry
#define NB_S 256                 // chunks/blocks for hist+scatter
#define BSH 9                    // bucket = dst >> 9  (512 nodes/bucket)
#define NPB 512                  // nodes per bucket
#define NBKT 196                 // ceil(100000/512)
#define SEG_CAP 8192             // LDS adj-segment capacity (mean ~6400, sd ~80)

// ---------------- scan helpers ----------------

#define SCAN_TPB 256
#define SCAN_IPT 4
#define SCAN_ELEMS 1024

__global__ void k_scan_partial(const int* __restrict__ in, int* __restrict__ outp,
                               int* __restrict__ blocksums, int n) {
    __shared__ int sd[SCAN_TPB];
    int tid = threadIdx.x;
    int base = blockIdx.x * SCAN_ELEMS + tid * SCAN_IPT;
    int v[SCAN_IPT]; int s = 0;
    for (int k = 0; k < SCAN_IPT; k++) { int idx = base + k; v[k] = (idx < n) ? in[idx] : 0; s += v[k]; }
    sd[tid] = s;
    __syncthreads();
    for (int off = 1; off < SCAN_TPB; off <<= 1) {
        int t = (tid >= off) ? sd[tid - off] : 0;
        __syncthreads();
        sd[tid] += t;
        __syncthreads();
    }
    int excl = sd[tid] - s;
    for (int k = 0; k < SCAN_IPT; k++) { int idx = base + k; if (idx < n) outp[idx] = excl; excl += v[k]; }
    if (tid == SCAN_TPB - 1) blocksums[blockIdx.x] = sd[tid];
}

__global__ void k_scan_blocks(int* __restrict__ bs, int nb) {
    __shared__ int sd[128];
    int t = threadIdx.x;
    int v = (t < nb) ? bs[t] : 0;
    sd[t] = v;
    __syncthreads();
    for (int off = 1; off < 128; off <<= 1) {
        int u = (t >= off) ? sd[t - off] : 0;
        __syncthreads();
        sd[t] += u;
        __syncthreads();
    }
    if (t < nb) bs[t] = sd[t] - v;
}

__global__ void k_scan_addg(int* __restrict__ arr, const int* __restrict__ bs, int n) {
    int i = blockIdx.x * blockDim.x + threadIdx.x;
    if (i < n) arr[i] += bs[i >> 10];
}

// ---------------- graph build: two-level counting sort ----------------
// k_hist: per-block LDS histogram of dst-buckets -> histT[bucket*NB_S + block]
__global__ __launch_bounds__(256) void k_hist(const int* __restrict__ dst,
                                              int* __restrict__ histT, int e) {
    __shared__ int lh[NBKT];
    int tid = threadIdx.x, k = blockIdx.x;
    if (tid < NBKT) lh[tid] = 0;
    __syncthreads();
    int chunk = (e + NB_S - 1) / NB_S;
    int i0 = k * chunk, i1 = min(i0 + chunk, e);
    for (int i = i0 + tid; i < i1; i += 256) atomicAdd(&lh[dst[i] >> BSH], 1);
    __syncthreads();
    if (tid < NBKT) histT[tid * NB_S + k] = lh[tid];
}

// k_scatter: place (src,dst) into bucket-sorted staging; coalesced-run writes
__global__ __launch_bounds__(256) void k_scatter(const int* __restrict__ edges,
                                                 const int* __restrict__ offs,
                                                 int2* __restrict__ staging, int e) {
    __shared__ int cur[NBKT];
    int tid = threadIdx.x, k = blockIdx.x;
    if (tid < NBKT) cur[tid] = offs[tid * NB_S + k];
    __syncthreads();
    int chunk = (e + NB_S - 1) / NB_S;
    int i0 = k * chunk, i1 = min(i0 + chunk, e);
    for (int i = i0 + tid; i < i1; i += 256) {
        int s = edges[i];
        int d = edges[e + i];
        int p = atomicAdd(&cur[d >> BSH], 1);
        staging[p] = make_int2(s, d);
    }
}

// k_bucket_fill: one block per bucket. Computes per-node deg (LDS), local scan
// -> writes rowptr+invd, places edges into LDS segment, streams adj coalesced.
__global__ __launch_bounds__(256) void k_bucket_fill(const int2* __restrict__ staging,
        const int* __restrict__ offs, int* __restrict__ rowptr,
        float* __restrict__ invd, int* __restrict__ adj, int n, int e) {
    __shared__ int ldeg[NPB];
    __shared__ int lrow[NPB];
    __shared__ int ps[256];
    __shared__ int lseg[SEG_CAP];
    int tid = threadIdx.x, b = blockIdx.x;
    int n0 = b << BSH;
    int nn = min(NPB, n - n0);
    int segBeg = offs[b * NB_S];
    int segEnd = (b == NBKT - 1) ? e : offs[(b + 1) * NB_S];

    ldeg[tid] = 0; ldeg[tid + 256] = 0;
    __syncthreads();
    for (int i = segBeg + tid; i < segEnd; i += 256)
        atomicAdd(&ldeg[staging[i].y - n0], 1);
    __syncthreads();

    // exclusive scan over 512 degrees (2 elems/thread + HS scan of partials)
    int a0 = ldeg[2 * tid], a1 = ldeg[2 * tid + 1];
    int s = a0 + a1;
    ps[tid] = s;
    __syncthreads();
    for (int off = 1; off < 256; off <<= 1) {
        int t = (tid >= off) ? ps[tid - off] : 0;
        __syncthreads();
        ps[tid] += t;
        __syncthreads();
    }
    int excl = ps[tid] - s;
    lrow[2 * tid] = excl;
    lrow[2 * tid + 1] = excl + a0;
    __syncthreads();

    for (int j = tid; j < nn; j += 256) {
        rowptr[n0 + j] = segBeg + lrow[j];
        int d = ldeg[j];
        invd[n0 + j] = (d > 0) ? (1.0f / (float)d) : 0.0f;
    }
    if (b == NBKT - 1 && tid == 0) rowptr[n] = e;
    __syncthreads();

    // place edges (cursor = lrow in place)
    for (int i = segBeg + tid; i < segEnd; i += 256) {
        int2 ed = staging[i];
        int p = atomicAdd(&lrow[ed.y - n0], 1);
        if (p < SEG_CAP) lseg[p] = ed.x;
        else adj[segBeg + p] = ed.x;   // never taken for this input (22-sigma)
    }
    __syncthreads();

    int m = segEnd - segBeg; if (m > SEG_CAP) m = SEG_CAP;
    for (int p = tid; p < m; p += 256) adj[segBeg + p] = lseg[p];
}

// ---------------- aggregation ----------------
// One wave per node, lane = feature, 8-wide latency-hiding unroll.

__global__ __launch_bounds__(256) void k_aggregate(const int* __restrict__ rowptr,
        const int* __restrict__ adj, const float* __restrict__ invd,
        const float* __restrict__ hin, float* __restrict__ agg, int n) {
    int wid = threadIdx.x >> 6, lane = threadIdx.x & 63;
    int node = blockIdx.x * 4 + wid;
    if (node >= n) return;
    int beg = rowptr[node], end = rowptr[node + 1];
    float acc = 0.0f;
    for (int e = beg; e < end; e += 8) {
        int idx[8];
        #pragma unroll
        for (int j = 0; j < 8; ++j) {
            int ee = e + j;
            idx[j] = adj[ee < end ? ee : end - 1];
        }
        float v[8];
        #pragma unroll
        for (int j = 0; j < 8; ++j) v[j] = hin[(size_t)idx[j] * HID_C + lane];
        #pragma unroll
        for (int j = 0; j < 8; ++j) acc += (e + j < end) ? v[j] : 0.0f;
    }
    agg[(size_t)node * HID_C + lane] = acc * invd[node];
}

// ---------------- tiled GEMM (64 rows x 64 cols, K=128, thread = 4x4 tile) ----
// MODE 0: encoder  A-row = x[g][0:128]                 W = encW[128][64]
// MODE 1: layer    A-row = agg[g][0:64] ++ hin[g][0:64] W = [Wl;Wr]
// MODE 2: pred     A-row = h[a_g] ++ h[b_g]             W = W1, + fused @W2+b2

__device__ __forceinline__ float4 ld4(const float* p) { return *(const float4*)p; }

template<int MODE>
__global__ __launch_bounds__(256, 2) void k_gemm(
    const float* __restrict__ A1, const float* __restrict__ A2,
    const int* __restrict__ pidx,
    const float* __restrict__ Ws1, const float* __restrict__ Ws2,
    const float* __restrict__ bias, const float* __restrict__ W2p,
    const float* __restrict__ b2p,
    float* __restrict__ outp, int nrows)
{
    __shared__ float AT[128 * 64];
    __shared__ float Wm[128 * 64];
    const int t = threadIdx.x;
    const int g0 = blockIdx.x * 64;

    #pragma unroll
    for (int p = 0; p < 8; ++p) {
        int k = p * 16 + (t >> 4);
        int c4 = (t & 15) * 4;
        float4 wv;
        if (MODE == 1) wv = (k < 64) ? ld4(Ws1 + k * 64 + c4) : ld4(Ws2 + (k - 64) * 64 + c4);
        else           wv = ld4(Ws1 + k * 64 + c4);
        *(float4*)&Wm[k * 64 + c4] = wv;
    }
    #pragma unroll
    for (int p = 0; p < 8; ++p) {
        int r = p * 8 + (t >> 5);
        int c = t & 31;
        int g = g0 + r; if (g > nrows - 1) g = nrows - 1;
        const float* ptr;
        if (MODE == 0)      ptr = A1 + (size_t)g * 128 + c * 4;
        else if (MODE == 1) ptr = (c < 16) ? (A1 + (size_t)g * 64 + c * 4)
                                           : (A2 + (size_t)g * 64 + (c - 16) * 4);
        else { int idx = pidx[2 * g + (c >> 4)]; ptr = A1 + (size_t)idx * 64 + (c & 15) * 4; }
        float4 av = ld4(ptr);
        int rs = r ^ ((c & 15) * 4);
        int base = c * 256 + rs;
        AT[base      ] = av.x;
        AT[base +  64] = av.y;
        AT[base + 128] = av.z;
        AT[base + 192] = av.w;
    }
    __syncthreads();

    const int tc = t & 15, tr = t >> 4;
    const int tc4 = tc * 4, tr4 = tr * 4;
    float4 acc0 = {0, 0, 0, 0}, acc1 = acc0, acc2 = acc0, acc3 = acc0;

    #pragma unroll 4
    for (int kc = 0; kc < 32; ++kc) {
        int abase = kc * 256 + (tr4 ^ ((kc & 15) * 4));
        int wbase = kc * 256 + tc4;
        #pragma unroll
        for (int i = 0; i < 4; ++i) {
            float4 aw = ld4(&AT[abase + i * 64]);
            float4 ww = ld4(&Wm[wbase + i * 64]);
            acc0.x = fmaf(aw.x, ww.x, acc0.x); acc0.y = fmaf(aw.x, ww.y, acc0.y);
            acc0.z = fmaf(aw.x, ww.z, acc0.z); acc0.w = fmaf(aw.x, ww.w, acc0.w);
            acc1.x = fmaf(aw.y, ww.x, acc1.x); acc1.y = fmaf(aw.y, ww.y, acc1.y);
            acc1.z = fmaf(aw.y, ww.z, acc1.z); acc1.w = fmaf(aw.y, ww.w, acc1.w);
            acc2.x = fmaf(aw.z, ww.x, acc2.x); acc2.y = fmaf(aw.z, ww.y, acc2.y);
            acc2.z = fmaf(aw.z, ww.z, acc2.z); acc2.w = fmaf(aw.z, ww.w, acc2.w);
            acc3.x = fmaf(aw.w, ww.x, acc3.x); acc3.y = fmaf(aw.w, ww.y, acc3.y);
            acc3.z = fmaf(aw.w, ww.z, acc3.z); acc3.w = fmaf(aw.w, ww.w, acc3.w);
        }
    }

    float4 bv = ld4(bias + tc4);
    float4 accs[4] = {acc0, acc1, acc2, acc3};
    if (MODE == 2) {
        float4 w2 = ld4(W2p + tc4);
        float bb = b2p[0];
        #pragma unroll
        for (int i = 0; i < 4; ++i) {
            float zx = fmaxf(accs[i].x + bv.x, 0.f);
            float zy = fmaxf(accs[i].y + bv.y, 0.f);
            float zz = fmaxf(accs[i].z + bv.z, 0.f);
            float zw = fmaxf(accs[i].w + bv.w, 0.f);
            float v = zx * w2.x + zy * w2.y + zz * w2.z + zw * w2.w;
            v += __shfl_down(v, 8, 64);
            v += __shfl_down(v, 4, 64);
            v += __shfl_down(v, 2, 64);
            v += __shfl_down(v, 1, 64);
            if (tc == 0) {
                int g = g0 + tr4 + i;
                if (g < nrows) outp[g] = v + bb;
            }
        }
    } else {
        #pragma unroll
        for (int i = 0; i < 4; ++i) {
            int g = g0 + tr4 + i;
            if (g < nrows) {
                float4 o;
                o.x = fmaxf(accs[i].x + bv.x, 0.f);
                o.y = fmaxf(accs[i].y + bv.y, 0.f);
                o.z = fmaxf(accs[i].z + bv.z, 0.f);
                o.w = fmaxf(accs[i].w + bv.w, 0.f);
                *(float4*)&outp[(size_t)g * 64 + tc4] = o;
            }
        }
    }
}

// ---------------- launch ----------------

extern "C" void kernel_launch(void* const* d_in, const int* in_sizes, int n_in,
                              void* d_out, int out_size, void* d_ws, size_t ws_size,
                              hipStream_t stream) {
    const float* x    = (const float*)d_in[0];
    const int*   edges= (const int*)d_in[1];
    const int*   pair = (const int*)d_in[2];
    const float* encW = (const float*)d_in[3];
    const float* encb = (const float*)d_in[4];
    const float* Wl   = (const float*)d_in[5];
    const float* bl   = (const float*)d_in[6];
    const float* Wr   = (const float*)d_in[7];
    const float* W1   = (const float*)d_in[8];
    const float* b1   = (const float*)d_in[9];
    const float* W2   = (const float*)d_in[10];
    const float* b2   = (const float*)d_in[11];
    float* out = (float*)d_out;

    const int N = N_NODES_C, E = N_EDGES_C, P = N_PAIRS_C;
    const int* dst = edges + E;
    const int M = NBKT * NB_S;   // hist matrix size = 50176

    char* w = (char*)d_ws;
    auto alloc = [&](size_t bytes) { char* p = w; w += (bytes + 255) & ~(size_t)255; return p; };
    int*   rowptr = (int*)alloc((size_t)(N + 1) * 4);
    int*   histT  = (int*)alloc((size_t)M * 4);
    int*   offs   = (int*)alloc((size_t)M * 4);
    int*   bsums  = (int*)alloc(128 * 4);
    float* invd   = (float*)alloc((size_t)N * 4);
    int*   adj    = (int*)alloc((size_t)E * 4);
    float* h0     = (float*)alloc((size_t)N * HID_C * 4);
    float* h1     = (float*)alloc((size_t)N * HID_C * 4);
    float* agg    = (float*)alloc((size_t)N * HID_C * 4);
    int2*  staging= (int2*)agg;   // alias: staging (10MB) dead before agg (25.6MB) is live

    int nscan = (M + SCAN_ELEMS - 1) / SCAN_ELEMS;   // 49

    hipLaunchKernelGGL(k_hist, dim3(NB_S), dim3(256), 0, stream, dst, histT, E);
    hipLaunchKernelGGL(k_scan_partial, dim3(nscan), dim3(SCAN_TPB), 0, stream, histT, offs, bsums, M);
    hipLaunchKernelGGL(k_scan_blocks, dim3(1), dim3(128), 0, stream, bsums, nscan);
    hipLaunchKernelGGL(k_scan_addg, dim3((M + 255) / 256), dim3(256), 0, stream, offs, bsums, M);
    hipLaunchKernelGGL(k_scatter, dim3(NB_S), dim3(256), 0, stream, edges, offs, staging, E);
    hipLaunchKernelGGL(k_bucket_fill, dim3(NBKT), dim3(256), 0, stream, staging, offs, rowptr, invd, adj, N, E);

    const int NB_N = (N + 63) / 64;
    const int NB_P = (P + 63) / 64;

    k_gemm<0><<<dim3(NB_N), dim3(256), 0, stream>>>(
        x, nullptr, nullptr, encW, nullptr, encb, nullptr, nullptr, h0, N);

    float* hc = h0; float* hn = h1;
    for (int l = 0; l < 3; l++) {
        hipLaunchKernelGGL(k_aggregate, dim3((N + 3) / 4), dim3(256), 0, stream,
                           rowptr, adj, invd, hc, agg, N);
        k_gemm<1><<<dim3(NB_N), dim3(256), 0, stream>>>(
            agg, hc, nullptr, Wl + (size_t)l * 64 * 64, Wr + (size_t)l * 64 * 64,
            bl + (size_t)l * 64, nullptr, nullptr, hn, N);
        float* tswap = hc; hc = hn; hn = tswap;
    }

    k_gemm<2><<<dim3(NB_P), dim3(256), 0, stream>>>(
        hc, nullptr, pair, W1, nullptr, b1, W2, b2, out, P);
}